// Round 1
// baseline (135.938 us; speedup 1.0000x reference)
//
#include <hip/hip_runtime.h>

// PointCrop2D: out[b,i,j,c] = in-bounds ? images[b, y-112+i, x-112+j, c] : -2.0f
// B=32, H=W=512, C=3, CROP=224, fill = (0-0.45)/0.225 = -2.0

#define B_N   32
#define H_N   512
#define W_N   512
#define C_N   3
#define CROP  224
#define DIA   112
#define FILLV (-2.0f)

__global__ __launch_bounds__(256)
void PointCrop2D_27943057227941_kernel(const float* __restrict__ points,
                                       const float* __restrict__ images,
                                       float* __restrict__ out)
{
    const int ROWF   = CROP * C_N;          // 672 floats per output row (div by 4)
    const int IMGF   = CROP * ROWF;         // 150528 floats per output image
    const int TOTALV = (B_N * IMGF) / 4;    // 1204224 float4 stores

    int g = blockIdx.x * blockDim.x + threadIdx.x;
    if (g >= TOTALV) return;

    int pflat = g * 4;
    int b   = pflat / IMGF;
    int rem = pflat - b * IMGF;
    int i   = rem / ROWF;
    int p   = rem - i * ROWF;               // [0,672), multiple of 4

    // points layout (B,3,3): x = points[b,0,0] -> b*9+0 ; y = points[b,1,0] -> b*9+3
    int xp = (int)points[b * 9 + 0];        // trunc == floor (values >= 0)
    int yp = (int)points[b * 9 + 3];
    int x  = min(max(xp, 1), W_N - 2);
    int y  = min(max(yp, 1), H_N - 2);

    int  r     = y - DIA + i;               // source image row
    bool rowok = (r >= 0) && (r <= H_N - 2);  // row 511 is fill by construction
    int  ra    = min(max(r, 0), H_N - 1);   // clamped for safe address formation
    int  colbase = x - DIA;                 // source col for output col j is colbase + j

    const float* rowptr = images + ((size_t)b * H_N + (size_t)ra) * (W_N * C_N);

    int j = p / 3;
    int c = p - j * 3;

    float4 v;
    float* vp = reinterpret_cast<float*>(&v);
#pragma unroll
    for (int k = 0; k < 4; ++k) {
        int  cc = colbase + j;
        bool ok = rowok && (cc >= 0) && (cc <= W_N - 2);   // col 511 is fill too
        int  cca = min(max(cc, 0), W_N - 1);
        vp[k] = ok ? rowptr[cca * 3 + c] : FILLV;
        ++c;
        if (c == 3) { c = 0; ++j; }
    }

    reinterpret_cast<float4*>(out)[g] = v;
}

extern "C" void kernel_launch(void* const* d_in, const int* in_sizes, int n_in,
                              void* d_out, int out_size, void* d_ws, size_t ws_size,
                              hipStream_t stream) {
    const float* points = (const float*)d_in[0];
    const float* images = (const float*)d_in[1];
    float* out = (float*)d_out;

    const int TOTALV = (B_N * CROP * CROP * C_N) / 4;   // 1204224
    const int block = 256;
    const int grid  = (TOTALV + block - 1) / block;     // 4704

    PointCrop2D_27943057227941_kernel<<<grid, block, 0, stream>>>(points, images, out);
}